// Round 1
// 372.778 us; speedup vs baseline: 1.4540x; 1.4540x over previous
//
#include <hip/hip_runtime.h>
#include <hip/hip_bf16.h>
#include <stdint.h>

typedef short bf16x8 __attribute__((ext_vector_type(8)));
typedef float f32x4 __attribute__((ext_vector_type(4)));
typedef unsigned short u16;
typedef unsigned int u32;

#define MFMA(a, b, c) __builtin_amdgcn_mfma_f32_16x16x32_bf16(a, b, c, 0, 0, 0)

#if __has_builtin(__builtin_amdgcn_exp2f)
#define EXP2F(x) __builtin_amdgcn_exp2f(x)
#else
#define EXP2F(x) exp2f(x)
#endif
#if __has_builtin(__builtin_amdgcn_rcpf)
#define RCPF(x) __builtin_amdgcn_rcpf(x)
#else
#define RCPF(x) (1.0f / (x))
#endif

__device__ __forceinline__ u16 f2bf(float f) {  // RNE f32->bf16 (finite inputs)
  u32 u = __builtin_bit_cast(u32, f);
  u += 0x7FFFu + ((u >> 16) & 1u);
  return (u16)(u >> 16);
}

// load 8 f32 (32B) and convert to 8 bf16 RNE
__device__ __forceinline__ bf16x8 cvt8(const float* p) {
  const float4 f0 = *(const float4*)p;
  const float4 f1 = *(const float4*)(p + 4);
  bf16x8 r;
  r[0] = (short)f2bf(f0.x); r[1] = (short)f2bf(f0.y);
  r[2] = (short)f2bf(f0.z); r[3] = (short)f2bf(f0.w);
  r[4] = (short)f2bf(f1.x); r[5] = (short)f2bf(f1.y);
  r[6] = (short)f2bf(f1.z); r[7] = (short)f2bf(f1.w);
  return r;
}

// async global->LDS, 16 bytes per lane. LDS dest is wave-uniform-base + lane*16
// (linear); swizzling is applied on the GLOBAL source address instead (m173).
__device__ __forceinline__ void async16(const u16* g, u16* l) {
  __builtin_amdgcn_global_load_lds(
      (const __attribute__((address_space(1))) void*)g,
      (__attribute__((address_space(3))) void*)l, 16, 0, 0);
}

// ---------------------------------------------------------------------------
// One-shot f32 -> bf16 conversion passes (memory-bound, ~30us combined).
// Split in two launches so the no-workspace fallback can reuse dead f32
// input buffers as bf16 homes without read/write races:
//   cvt_qk: Xq, Xk        (homes in d_out: 2T u16 capacity exactly)
//   cvt_vw: Xv, Wq..Wo    (homes in d_in[0], dead after cvt_qk ran)
// Each block converts 2048 elems (256 thr x 8).
// ---------------------------------------------------------------------------
__global__ __launch_bounds__(256) void cvt_qk(const float* __restrict__ xq,
                                              const float* __restrict__ xk,
                                              u16* __restrict__ dq,
                                              u16* __restrict__ dk) {
  int b = (int)blockIdx.x;
  const float* s;
  u16* d;
  if (b < 4096) { s = xq; d = dq; } else { s = xk; d = dk; b -= 4096; }
  const size_t off = (size_t)b * 2048 + (size_t)threadIdx.x * 8;
  *(bf16x8*)(d + off) = cvt8(s + off);
}

__global__ __launch_bounds__(256) void cvt_vw(
    const float* __restrict__ xv, const float* __restrict__ wq,
    const float* __restrict__ wk, const float* __restrict__ wv,
    const float* __restrict__ wo, u16* __restrict__ dv, u16* __restrict__ dwq,
    u16* __restrict__ dwk, u16* __restrict__ dwv, u16* __restrict__ dwo) {
  int b = (int)blockIdx.x;
  const float* s;
  u16* d;
  if (b < 4096) { s = xv; d = dv; }
  else if (b < 4608) { s = wq; d = dwq; b -= 4096; }
  else if (b < 5120) { s = wk; d = dwk; b -= 4608; }
  else if (b < 5632) { s = wv; d = dwv; b -= 5120; }
  else { s = wo; d = dwo; b -= 5632; }
  const size_t off = (size_t)b * 2048 + (size_t)threadIdx.x * 8;
  *(bf16x8*)(d + off) = cvt8(s + off);
}

// ---------------------------------------------------------------------------
// NT GEMM: out[m,n] = sum_k A[m,k]*W[n,k]; M=8192, N=K=1024. A and W are bf16
// (pre-converted). Staging via global_load_lds width=16: LDS dest linear,
// XOR swizzle (blk ^ (row&7)) applied to the global source address so the
// ds_read_b128 fragment reads stay conflict-free. 128x128 tile, BK=64,
// 4 waves, 4x4 16x16x32 MFMA tiles/wave.
// MODE 0: row-major out (M x 1024), OutT=float (final output)
// MODE 1: per-head out[((b*16+h)*2048+nr)*64 + d], OutT=u16        (Q, K)
// MODE 2: per-head transposed out[((b*16+h)*64+d)*2048+nr], OutT=u16 (V^T)
// ---------------------------------------------------------------------------
template <int MODE, typename OutT>
__global__ __launch_bounds__(256, 2) void gemm_bt(const u16* __restrict__ A,
                                                  const u16* __restrict__ W,
                                                  OutT* __restrict__ out) {
  __shared__ u16 smA[128 * 64];
  __shared__ u16 smB[128 * 64];
  const int tid = (int)threadIdx.x;
  const int w = tid >> 6, l = tid & 63;
  const int la = l & 15, q = l >> 4;
  const int m0 = blockIdx.x * 128, n0 = blockIdx.y * 128;
  const int wm = w >> 1, wn = w & 1;

  // per-thread staging geometry (constant across kk)
  const int srow = tid >> 3, sblk = tid & 7;  // +jj*32 rows per sub-issue
  f32x4 acc[4][4];
#pragma unroll
  for (int i = 0; i < 4; ++i)
#pragma unroll
    for (int j = 0; j < 4; ++j) acc[i][j] = (f32x4){0.f, 0.f, 0.f, 0.f};

  for (int kk = 0; kk < 16; ++kk) {
    __syncthreads();
#pragma unroll
    for (int jj = 0; jj < 4; ++jj) {
      const int row = jj * 32 + srow;
      const int sb = (sblk ^ (row & 7)) * 8;  // pre-swizzled global source
      const int ld = (jj * 256 + tid) * 8;    // linear LDS dest
      async16(A + (size_t)(m0 + row) * 1024 + kk * 64 + sb, smA + ld);
      async16(W + (size_t)(n0 + row) * 1024 + kk * 64 + sb, smB + ld);
    }
    __syncthreads();  // compiler emits vmcnt(0) drain for global_load_lds
#pragma unroll
    for (int ks = 0; ks < 2; ++ks) {
      bf16x8 af[4], bfr[4];
#pragma unroll
      for (int im = 0; im < 4; ++im)
        af[im] = *(const bf16x8*)(smA + (wm * 64 + im * 16 + la) * 64 +
                                  (((ks * 4 + q) ^ (la & 7)) * 8));
#pragma unroll
      for (int in = 0; in < 4; ++in)
        bfr[in] = *(const bf16x8*)(smB + (wn * 64 + in * 16 + la) * 64 +
                                   (((ks * 4 + q) ^ (la & 7)) * 8));
#pragma unroll
      for (int im = 0; im < 4; ++im)
#pragma unroll
        for (int in = 0; in < 4; ++in)
          acc[im][in] = MFMA(af[im], bfr[in], acc[im][in]);
    }
  }

  // epilogue: C/D layout col = la (n), row = q*4 + r (m)
#pragma unroll
  for (int im = 0; im < 4; ++im) {
    const int mbase = m0 + wm * 64 + im * 16 + q * 4;
#pragma unroll
    for (int in = 0; in < 4; ++in) {
      const int n = n0 + wn * 64 + in * 16 + la;
      if (MODE == 2) {
        const int b = mbase >> 11, nr = mbase & 2047;
        const int h = n >> 6, d = n & 63;
        uint2 val;
        val.x = (u32)f2bf(acc[im][in][0]) | ((u32)f2bf(acc[im][in][1]) << 16);
        val.y = (u32)f2bf(acc[im][in][2]) | ((u32)f2bf(acc[im][in][3]) << 16);
        *(uint2*)((u16*)out + ((size_t)((b * 16 + h) * 64 + d)) * 2048 + nr) = val;
      } else if (MODE == 0) {
#pragma unroll
        for (int r = 0; r < 4; ++r) {
          const int mm = mbase + r;
          ((float*)out)[(size_t)mm * 1024 + n] = acc[im][in][r];  // f32 output
        }
      } else {
#pragma unroll
        for (int r = 0; r < 4; ++r) {
          const int mm = mbase + r;
          const int b = mm >> 11, nr = mm & 2047;
          const int h = n >> 6, d = n & 63;
          ((u16*)out)[((size_t)((b * 16 + h) * 2048 + nr)) * 64 + d] = f2bf(acc[im][in][r]);
        }
      }
    }
  }
}

// ---------------------------------------------------------------------------
// Flash attention. Grid (16 q-tiles, 64 b*h). Block 256 (4 waves).
// Q (bh,2048,64), K (bh,2048,64), VT (bh,64,2048) bf16 -> ctx (4,2048,1024) bf16.
// S^T = K·Q^T (A=Kfrag, B=Qfrag): lane holds 4 consecutive j -> packed 8B P
// writes. PV: O += MFMA(A=Pfrag, B=VTfrag). alpha/l broadcast via __shfl
// (no LDS) so total static LDS = exactly 64 KB.
// ---------------------------------------------------------------------------
__global__ __launch_bounds__(256, 2) void attn_kernel(const u16* __restrict__ Qh,
                                                      const u16* __restrict__ Kh,
                                                      const u16* __restrict__ VT,
                                                      u16* __restrict__ ctx) {
  __shared__ u16 smK[128 * 64];   // K tile, swizzled ^(row&7), stride 64
  __shared__ u16 smV[64 * 128];   // V^T tile, swizzled ^(row&15), stride 128
  __shared__ u16 smP[128 * 128];  // P (i x j), 8-elem blocks swizzled ^(i&15)

  const int tid = (int)threadIdx.x;
  const int w = tid >> 6, l = tid & 63;
  const int la = l & 15, q = l >> 4;
  const int qt = blockIdx.x, bh = blockIdx.y;
  const u16* Qp = Qh + (size_t)bh * (2048 * 64);
  const u16* Kp = Kh + (size_t)bh * (2048 * 64);
  const u16* Vp = VT + (size_t)bh * (64 * 2048);

  // Q fragments (B-operand: n = lane&15 -> q-row, k = q*8+j)
  bf16x8 qf[2][2];
#pragma unroll
  for (int ic = 0; ic < 2; ++ic)
#pragma unroll
    for (int ks = 0; ks < 2; ++ks)
      qf[ic][ks] = *(const bf16x8*)(Qp + (size_t)(qt * 128 + w * 32 + ic * 16 + la) * 64 +
                                    ks * 32 + q * 8);

  f32x4 accO[2][4];
#pragma unroll
  for (int ic = 0; ic < 2; ++ic)
#pragma unroll
    for (int dc = 0; dc < 4; ++dc) accO[ic][dc] = (f32x4){0.f, 0.f, 0.f, 0.f};
  float m_[2] = {-__builtin_inff(), -__builtin_inff()};
  float l_[2] = {0.f, 0.f};
  float alpha_[2];
  const float SC = 0.18033688011112042f;  // log2(e) / sqrt(64)

  for (int kt = 0; kt < 16; ++kt) {
    __syncthreads();  // prior-iter LDS reads done before restage
#pragma unroll
    for (int jj = 0; jj < 4; ++jj) {
      const int idx = jj * 256 + tid;
      const int kr = idx >> 3, kb = idx & 7;  // K tile: 128 rows x 64 k
      const bf16x8 vk = *(const bf16x8*)(Kp + (size_t)(kt * 128 + kr) * 64 + kb * 8);
      *(bf16x8*)(smK + kr * 64 + ((kb ^ (kr & 7)) * 8)) = vk;
      const int vr = idx >> 4, vb = idx & 15;  // V^T tile: 64 rows (d) x 128 j
      const bf16x8 vv = *(const bf16x8*)(Vp + (size_t)vr * 2048 + kt * 128 + vb * 8);
      *(bf16x8*)(smV + vr * 128 + ((vb ^ (vr & 15)) * 8)) = vv;
    }
    __syncthreads();

    // S^T tiles: m = j (8 chunks), n = i (wave's 2 chunks)
    f32x4 st[2][8];
#pragma unroll
    for (int ic = 0; ic < 2; ++ic)
#pragma unroll
      for (int jc = 0; jc < 8; ++jc) st[ic][jc] = (f32x4){0.f, 0.f, 0.f, 0.f};
#pragma unroll
    for (int ks = 0; ks < 2; ++ks) {
      bf16x8 kf[8];
#pragma unroll
      for (int jc = 0; jc < 8; ++jc)
        kf[jc] = *(const bf16x8*)(smK + (jc * 16 + la) * 64 +
                                  (((ks * 4 + q) ^ (la & 7)) * 8));
#pragma unroll
      for (int jc = 0; jc < 8; ++jc)
#pragma unroll
        for (int ic = 0; ic < 2; ++ic)
          st[ic][jc] = MFMA(kf[jc], qf[ic][ks], st[ic][jc]);
    }

    // online softmax; lane owns row i = w*32+ic*16+la, j = jc*16 + q*4 + r
#pragma unroll
    for (int ic = 0; ic < 2; ++ic) {
      float mx = -__builtin_inff();
#pragma unroll
      for (int jc = 0; jc < 8; ++jc)
#pragma unroll
        for (int r = 0; r < 4; ++r) {
          const float t = st[ic][jc][r] * SC;
          st[ic][jc][r] = t;
          mx = fmaxf(mx, t);
        }
      mx = fmaxf(mx, __shfl_xor(mx, 16));
      mx = fmaxf(mx, __shfl_xor(mx, 32));
      const float mnew = fmaxf(m_[ic], mx);
      alpha_[ic] = EXP2F(m_[ic] - mnew);
      float rs = 0.f;
      const int i = w * 32 + ic * 16 + la;
#pragma unroll
      for (int jc = 0; jc < 8; ++jc) {
        const float p0 = EXP2F(st[ic][jc][0] - mnew);
        const float p1 = EXP2F(st[ic][jc][1] - mnew);
        const float p2 = EXP2F(st[ic][jc][2] - mnew);
        const float p3 = EXP2F(st[ic][jc][3] - mnew);
        rs += (p0 + p1) + (p2 + p3);
        uint2 val;
        val.x = (u32)f2bf(p0) | ((u32)f2bf(p1) << 16);
        val.y = (u32)f2bf(p2) | ((u32)f2bf(p3) << 16);
        const int blk = (jc * 2 + (q >> 1)) ^ la;  // logical 8-blk ^ (i&15)
        *(uint2*)(smP + i * 128 + blk * 8 + (q & 1) * 4) = val;
      }
      rs += __shfl_xor(rs, 16);
      rs += __shfl_xor(rs, 32);
      m_[ic] = mnew;
      l_[ic] = l_[ic] * alpha_[ic] + rs;
    }
    __syncthreads();  // P visible

    // rescale O by alpha (O rows q*4+r; alpha for row base+t lives in lane t<16)
#pragma unroll
    for (int ic = 0; ic < 2; ++ic)
#pragma unroll
      for (int r = 0; r < 4; ++r) {
        const float a = __shfl(alpha_[ic], q * 4 + r);
#pragma unroll
        for (int dc = 0; dc < 4; ++dc) accO[ic][dc][r] *= a;
      }

    // PV: O[i,d] += sum_j P[i,j] V^T[d,j]
#pragma unroll
    for (int ks = 0; ks < 4; ++ks) {
      bf16x8 pf[2], vf[4];
#pragma unroll
      for (int ic = 0; ic < 2; ++ic)
        pf[ic] = *(const bf16x8*)(smP + (w * 32 + ic * 16 + la) * 128 +
                                  (((ks * 4 + q) ^ la) * 8));
#pragma unroll
      for (int dc = 0; dc < 4; ++dc)
        vf[dc] = *(const bf16x8*)(smV + (dc * 16 + la) * 128 +
                                  (((ks * 4 + q) ^ la) * 8));
#pragma unroll
      for (int ic = 0; ic < 2; ++ic)
#pragma unroll
        for (int dc = 0; dc < 4; ++dc)
          accO[ic][dc] = MFMA(pf[ic], vf[dc], accO[ic][dc]);
    }
  }

  // epilogue: O / l  (l for row base+t lives in lane t<16)
  const int b = bh >> 4, h = bh & 15;
#pragma unroll
  for (int ic = 0; ic < 2; ++ic)
#pragma unroll
    for (int r = 0; r < 4; ++r) {
      const float inv = RCPF(__shfl(l_[ic], q * 4 + r));
      const size_t rowoff =
          ((size_t)(b * 2048 + qt * 128 + w * 32 + ic * 16 + q * 4 + r)) * 1024 + h * 64;
#pragma unroll
      for (int dc = 0; dc < 4; ++dc)
        ctx[rowoff + dc * 16 + la] = f2bf(accO[ic][dc][r] * inv);
    }
}

// ---------------------------------------------------------------------------
extern "C" void kernel_launch(void* const* d_in, const int* in_sizes, int n_in,
                              void* d_out, int out_size, void* d_ws, size_t ws_size,
                              hipStream_t stream) {
  const float* Xq = (const float*)d_in[0];
  const float* Xk = (const float*)d_in[1];
  const float* Xv = (const float*)d_in[2];
  const float* Wq = (const float*)d_in[3];
  const float* Wk = (const float*)d_in[4];
  const float* Wv = (const float*)d_in[5];
  const float* Wo = (const float*)d_in[6];

  const size_t T = 8388608;   // 4*2048*1024 elems (X/intermediate, bf16)
  const size_t WN = 1048576;  // 1024*1024 elems (W, bf16)
  u16 *Xqb, *Xkb, *Xvb, *Wqb, *Wkb, *Wvb, *Wob, *Qh, *Kh, *VTp, *ctx;
  if (ws_size >= (7 * T + 4 * WN) * sizeof(u16)) {
    u16* ws = (u16*)d_ws;
    Xqb = ws; Xkb = ws + T; Xvb = ws + 2 * T;
    Qh = ws + 3 * T; Kh = ws + 4 * T; VTp = ws + 5 * T; ctx = ws + 6 * T;
    Wqb = ws + 7 * T; Wkb = Wqb + WN; Wvb = Wkb + WN; Wob = Wvb + WN;
  } else {
    // Fallback: reuse dead buffers (harness restores d_in before every launch;
    // kernels serialize on `stream`). Capacities in u16: d_out = 2T, each f32
    // X input buffer = 2T. Lifetime-safe assignment:
    //   cvt_qk:  Xq,Xk (f32) -> d_out[0:T], d_out[T:2T]      (Xq,Xk f32 die)
    //   cvt_vw:  Xv -> Xq-buf[0:T]; W's -> Xq-buf[T:T+4WN]   (Xv f32 dies)
    //   gemm Q/K write Qh/Kh into Xk-buf halves (dead f32)
    //   gemm V writes VT into Xv-buf[0:T]; attn ctx -> Xv-buf[T:2T]
    //   final gemm reads ctx, writes f32 d_out (Xqb/Xkb dead by then)
    u16* ob = (u16*)d_out;
    u16* bq = (u16*)d_in[0];
    u16* bk = (u16*)d_in[1];
    u16* bv = (u16*)d_in[2];
    Xqb = ob; Xkb = ob + T;
    Xvb = bq; Wqb = bq + T; Wkb = Wqb + WN; Wvb = Wkb + WN; Wob = Wvb + WN;
    Qh = bk; Kh = bk + T;
    VTp = bv; ctx = bv + T;
  }

  dim3 blk(256);
  hipLaunchKernelGGL(cvt_qk, dim3(8192), blk, 0, stream, Xq, Xk, Xqb, Xkb);
  hipLaunchKernelGGL(cvt_vw, dim3(6144), blk, 0, stream, Xv, Wq, Wk, Wv, Wo,
                     Xvb, Wqb, Wkb, Wvb, Wob);
  dim3 gg(64, 8);  // 8192/128 x 1024/128
  hipLaunchKernelGGL((gemm_bt<1, u16>), gg, blk, 0, stream, Xqb, Wqb, Qh);
  hipLaunchKernelGGL((gemm_bt<1, u16>), gg, blk, 0, stream, Xkb, Wkb, Kh);
  hipLaunchKernelGGL((gemm_bt<2, u16>), gg, blk, 0, stream, Xvb, Wvb, VTp);
  hipLaunchKernelGGL(attn_kernel, dim3(16, 64), blk, 0, stream, Qh, Kh, VTp, ctx);
  hipLaunchKernelGGL((gemm_bt<0, float>), gg, blk, 0, stream, ctx, Wob, (float*)d_out);
}